// Round 1
// baseline (13050.557 us; speedup 1.0000x reference)
//
#include <hip/hip_runtime.h>

#define C 128
#define EPS 1e-5f

// ---------- block-wide (128-thread) sum reduction ----------
__device__ __forceinline__ float block_reduce_sum_128(float v, float* buf) {
    // 128 threads = 2 waves of 64
    for (int off = 32; off > 0; off >>= 1) v += __shfl_down(v, off, 64);
    int t = threadIdx.x;
    __syncthreads();                 // protect buf reuse across calls
    if ((t & 63) == 0) buf[t >> 6] = v;
    __syncthreads();
    return buf[0] + buf[1];
}

// ---------- stem: feat = relu(gn(relu(ctrs@W1+b1)@W2) + gn(relu(feats@Ws1+bs1)@Ws2)) ----------
__global__ void stem_kernel(const float* __restrict__ ctrs, const float* __restrict__ feats,
    const float* __restrict__ W_in1, const float* __restrict__ b_in1, const float* __restrict__ W_in2,
    const float* __restrict__ g_in, const float* __restrict__ bb_in,
    const float* __restrict__ W_seg1, const float* __restrict__ b_seg1, const float* __restrict__ W_seg2,
    const float* __restrict__ g_seg, const float* __restrict__ bb_seg,
    float* __restrict__ A)
{
    int n = blockIdx.x;
    int c = threadIdx.x;
    __shared__ float h[C];
    __shared__ float red[2];

    // path 1: ctrs
    float c0 = ctrs[2 * n], c1 = ctrs[2 * n + 1];
    float hv = fmaxf(0.f, fmaf(c0, W_in1[c], fmaf(c1, W_in1[C + c], b_in1[c])));
    h[c] = hv;
    __syncthreads();
    float y = 0.f;
    #pragma unroll 8
    for (int k = 0; k < C; ++k) y = fmaf(h[k], W_in2[k * C + c], y);
    float m = block_reduce_sum_128(y, red) * (1.f / C);
    float d = y - m;
    float var = block_reduce_sum_128(d * d, red) * (1.f / C);
    float o1 = d * rsqrtf(var + EPS) * g_in[c] + bb_in[c];

    // path 2: feats
    float f0 = feats[2 * n], f1 = feats[2 * n + 1];
    __syncthreads();   // everyone done reading h (reduces above already synced, belt+braces)
    float hv2 = fmaxf(0.f, fmaf(f0, W_seg1[c], fmaf(f1, W_seg1[C + c], b_seg1[c])));
    h[c] = hv2;
    __syncthreads();
    float y2 = 0.f;
    #pragma unroll 8
    for (int k = 0; k < C; ++k) y2 = fmaf(h[k], W_seg2[k * C + c], y2);
    float m2 = block_reduce_sum_128(y2, red) * (1.f / C);
    float d2 = y2 - m2;
    float v2 = block_reduce_sum_128(d2 * d2, red) * (1.f / C);
    float o2 = d2 * rsqrtf(v2 + EPS) * g_seg[c] + bb_seg[c];

    A[n * C + c] = fmaxf(0.f, o1 + o2);
}

// ---------- dense per-row matvec: Y[n] = X[n] @ W ----------
__global__ void matvec_kernel(const float* __restrict__ X, const float* __restrict__ W,
                              float* __restrict__ Y)
{
    int n = blockIdx.x, c = threadIdx.x;
    __shared__ float row[C];
    row[c] = X[n * C + c];
    __syncthreads();
    float y = 0.f;
    #pragma unroll 8
    for (int k = 0; k < C; ++k) y = fmaf(row[k], W[k * C + c], y);
    Y[n * C + c] = y;
}

// ---------- edge gather-matvec-scatter: T[u[e]] += X[v[e]] @ W ----------
__global__ void edge_kernel(const int* __restrict__ u, const int* __restrict__ v,
                            const float* __restrict__ X, const float* __restrict__ W,
                            float* __restrict__ T)
{
    int e = blockIdx.x, c = threadIdx.x;
    int dst = u[e], src = v[e];
    __shared__ float row[C];
    row[c] = X[src * C + c];
    __syncthreads();
    float y = 0.f;
    #pragma unroll 8
    for (int k = 0; k < C; ++k) y = fmaf(row[k], W[k * C + c], y);
    atomicAdd(&T[dst * C + c], y);
}

// ---------- tail: A = relu(gn2(relu(gn1(T)) @ W2) + A); out = A ----------
__global__ void tail_kernel(const float* __restrict__ T, float* __restrict__ A,
    const float* __restrict__ g1, const float* __restrict__ b1,
    const float* __restrict__ W2, const float* __restrict__ g2, const float* __restrict__ b2,
    float* __restrict__ out)
{
    int n = blockIdx.x, c = threadIdx.x;
    __shared__ float row[C];
    __shared__ float red[2];

    float t = T[n * C + c];
    float m = block_reduce_sum_128(t, red) * (1.f / C);
    float d = t - m;
    float var = block_reduce_sum_128(d * d, red) * (1.f / C);
    float x = fmaxf(0.f, d * rsqrtf(var + EPS) * g1[c] + b1[c]);
    row[c] = x;
    __syncthreads();
    float y = 0.f;
    #pragma unroll 8
    for (int k = 0; k < C; ++k) y = fmaf(row[k], W2[k * C + c], y);
    float m2 = block_reduce_sum_128(y, red) * (1.f / C);
    float d2 = y - m2;
    float v2 = block_reduce_sum_128(d2 * d2, red) * (1.f / C);
    float z = d2 * rsqrtf(v2 + EPS) * g2[c] + b2[c];
    float r = fmaxf(0.f, z + A[n * C + c]);
    A[n * C + c] = r;
    out[n * C + c] = r;
}

extern "C" void kernel_launch(void* const* d_in, const int* in_sizes, int n_in,
                              void* d_out, int out_size, void* d_ws, size_t ws_size,
                              hipStream_t stream)
{
    const float* ctrs   = (const float*)d_in[0];
    const float* feats  = (const float*)d_in[1];
    const int*   pre_u  = (const int*)d_in[2];
    const int*   pre_v  = (const int*)d_in[3];
    const int*   suc_u  = (const int*)d_in[4];
    const int*   suc_v  = (const int*)d_in[5];
    const int*   left_u = (const int*)d_in[6];
    const int*   left_v = (const int*)d_in[7];
    const int*   right_u= (const int*)d_in[8];
    const int*   right_v= (const int*)d_in[9];
    const float* W_in1  = (const float*)d_in[10];
    const float* b_in1  = (const float*)d_in[11];
    const float* W_in2  = (const float*)d_in[12];
    const float* g_in   = (const float*)d_in[13];
    const float* bb_in  = (const float*)d_in[14];
    const float* W_seg1 = (const float*)d_in[15];
    const float* b_seg1 = (const float*)d_in[16];
    const float* W_seg2 = (const float*)d_in[17];
    const float* g_seg  = (const float*)d_in[18];
    const float* bb_seg = (const float*)d_in[19];
    const float* W_ctr  = (const float*)d_in[20];
    const float* W_pre  = (const float*)d_in[21];
    const float* W_suc  = (const float*)d_in[22];
    const float* W_left = (const float*)d_in[23];
    const float* W_right= (const float*)d_in[24];
    const float* g_norm = (const float*)d_in[25];
    const float* b_norm = (const float*)d_in[26];
    const float* W_ctr2 = (const float*)d_in[27];
    const float* g_ctr2 = (const float*)d_in[28];
    const float* b_ctr2 = (const float*)d_in[29];

    const int N  = in_sizes[0] / 2;         // 200000
    const int S  = 6;                        // structural constant from reference
    const int E  = in_sizes[2] / S;          // 200000
    const int E2 = in_sizes[6];              // 100000
    const int B  = in_sizes[20] / (C * C);   // 2

    // workspace: A (feat/res) and T (temp), each N*C floats
    float* A = (float*)d_ws;
    float* T = A + (size_t)N * C;
    float* out = (float*)d_out;

    dim3 blk(C);

    stem_kernel<<<N, blk, 0, stream>>>(ctrs, feats,
        W_in1, b_in1, W_in2, g_in, bb_in,
        W_seg1, b_seg1, W_seg2, g_seg, bb_seg, A);

    for (int i = 0; i < B; ++i) {
        matvec_kernel<<<N, blk, 0, stream>>>(A, W_ctr + (size_t)i * C * C, T);
        for (int s = 0; s < S; ++s) {
            edge_kernel<<<E, blk, 0, stream>>>(pre_u + (size_t)s * E, pre_v + (size_t)s * E,
                A, W_pre + ((size_t)i * S + s) * C * C, T);
            edge_kernel<<<E, blk, 0, stream>>>(suc_u + (size_t)s * E, suc_v + (size_t)s * E,
                A, W_suc + ((size_t)i * S + s) * C * C, T);
        }
        edge_kernel<<<E2, blk, 0, stream>>>(left_u, left_v,
            A, W_left + (size_t)i * C * C, T);
        edge_kernel<<<E2, blk, 0, stream>>>(right_u, right_v,
            A, W_right + (size_t)i * C * C, T);
        tail_kernel<<<N, blk, 0, stream>>>(T, A,
            g_norm + (size_t)i * C, b_norm + (size_t)i * C,
            W_ctr2 + (size_t)i * C * C,
            g_ctr2 + (size_t)i * C, b_ctr2 + (size_t)i * C, out);
    }
}

// Round 3
// 2996.583 us; speedup vs baseline: 4.3551x; 4.3551x over previous
//
#include <hip/hip_runtime.h>

#define C 128
#define EPS 1e-5f

typedef __bf16 bf16x8 __attribute__((ext_vector_type(8)));
typedef float f32x4 __attribute__((ext_vector_type(4)));

__device__ __forceinline__ unsigned short f2bf(float f) {
    unsigned int u = __float_as_uint(f);
    unsigned int r = (u + 0x7FFFu + ((u >> 16) & 1u)) >> 16;   // RNE
    return (unsigned short)r;
}

// ---------------- weight convert: WT[m][col][k] = bf16(W_m[k][col]) ----------------
struct WPtrs { const float* p[34]; };

__global__ __launch_bounds__(128) void convert_weights(WPtrs wp, unsigned short* __restrict__ WT)
{
    int m = blockIdx.y, k = blockIdx.x, c = threadIdx.x;      // grid (128, 34)
    float val = wp.p[m][k * C + c];
    WT[((size_t)m * C + c) * C + k] = f2bf(val);
}

// ---------------- stem elementwise: H = bf16(relu(in2 @ W1 + b1)) ----------------
__global__ __launch_bounds__(256) void stem_pre(const float* __restrict__ in2,
    const float* __restrict__ W1, const float* __restrict__ b1,
    unsigned short* __restrict__ H, int N)
{
    int idx = blockIdx.x * 256 + threadIdx.x;
    if (idx >= N * C) return;
    int n = idx >> 7, c = idx & 127;
    float h = fmaxf(0.f, fmaf(in2[2 * n], W1[c], fmaf(in2[2 * n + 1], W1[C + c], b1[c])));
    H[idx] = f2bf(h);
}

// ---------------- dense GEMM: Y[128-row tile] = X(bf16) @ W (WT = W^T bf16) ----------------
__global__ __launch_bounds__(256) void gemm_dense(const unsigned short* __restrict__ X,
    const unsigned short* __restrict__ WT, float* __restrict__ Y, int N)
{
    __shared__ unsigned short Xs[128][136];
    __shared__ unsigned short Ws[128][136];
    int tid = threadIdx.x;
    int base = blockIdx.x * 128;

    {   // load X tile: 2 threads per row, 128B each
        int r = tid >> 1, h = (tid & 1) * 64;
        int gr = base + r; if (gr >= N) gr = N - 1;
        const uint4* src = (const uint4*)(X + (size_t)gr * C + h);
        uint4* dst = (uint4*)(&Xs[r][h]);
        #pragma unroll
        for (int it = 0; it < 8; ++it) dst[it] = src[it];
    }
    {   // load W^T tile
        int r = tid >> 1, h = (tid & 1) * 64;
        const uint4* src = (const uint4*)(WT + (size_t)r * C + h);
        uint4* dst = (uint4*)(&Ws[r][h]);
        #pragma unroll
        for (int it = 0; it < 8; ++it) dst[it] = src[it];
    }
    __syncthreads();

    int w = tid >> 6, l = tid & 63;
    int lr = l & 15, lk = (l >> 4) * 8;
    f32x4 acc[2][8];
    #pragma unroll
    for (int m = 0; m < 2; ++m)
        #pragma unroll
        for (int n = 0; n < 8; ++n) acc[m][n] = (f32x4){0.f, 0.f, 0.f, 0.f};

    #pragma unroll
    for (int kk = 0; kk < 4; ++kk) {
        bf16x8 a0 = *(const bf16x8*)&Xs[w * 32 + lr][kk * 32 + lk];
        bf16x8 a1 = *(const bf16x8*)&Xs[w * 32 + 16 + lr][kk * 32 + lk];
        #pragma unroll
        for (int n = 0; n < 8; ++n) {
            bf16x8 b = *(const bf16x8*)&Ws[n * 16 + lr][kk * 32 + lk];
            acc[0][n] = __builtin_amdgcn_mfma_f32_16x16x32_bf16(a0, b, acc[0][n], 0, 0, 0);
            acc[1][n] = __builtin_amdgcn_mfma_f32_16x16x32_bf16(a1, b, acc[1][n], 0, 0, 0);
        }
    }

    #pragma unroll
    for (int m = 0; m < 2; ++m)
        #pragma unroll
        for (int n = 0; n < 8; ++n)
            #pragma unroll
            for (int q = 0; q < 4; ++q) {
                int row = base + w * 32 + m * 16 + (l >> 4) * 4 + q;
                if (row < N) Y[(size_t)row * C + n * 16 + lr] = acc[m][n][q];
            }
}

// ---------------- edge GEMM: T[u[e]] += featB[v[e]] @ W, 128 edges per tile ----------------
__global__ __launch_bounds__(256) void edge_gemm(const unsigned short* __restrict__ featB,
    const int* __restrict__ pre_u, const int* __restrict__ pre_v,
    const int* __restrict__ suc_u, const int* __restrict__ suc_v,
    const int* __restrict__ left_u, const int* __restrict__ left_v,
    const int* __restrict__ right_u, const int* __restrict__ right_v,
    const unsigned short* __restrict__ WTb,   // block's WT base; sets at (1+set)*C*C
    float* __restrict__ T, int E, int E2)
{
    int set = blockIdx.y;
    const int *u, *v; int len; const unsigned short* Wt;
    if (set < 6)       { u = pre_u + (size_t)set * E;       v = pre_v + (size_t)set * E;       len = E; }
    else if (set < 12) { u = suc_u + (size_t)(set - 6) * E; v = suc_v + (size_t)(set - 6) * E; len = E; }
    else if (set == 12){ u = left_u;  v = left_v;  len = E2; }
    else               { u = right_u; v = right_v; len = E2; }
    Wt = WTb + (size_t)(1 + set) * C * C;

    int base = blockIdx.x * 128;
    if (base >= len) return;

    __shared__ unsigned short Xs[128][136];
    __shared__ unsigned short Ws[128][136];
    __shared__ int us[128];

    int tid = threadIdx.x;
    if (tid < 128) us[tid] = (base + tid < len) ? u[base + tid] : -1;
    {   // gather rows of featB
        int r = tid >> 1, h = (tid & 1) * 64;
        int e = base + r;
        int vv = (e < len) ? v[e] : 0;
        const uint4* src = (const uint4*)(featB + (size_t)vv * C + h);
        uint4* dst = (uint4*)(&Xs[r][h]);
        #pragma unroll
        for (int it = 0; it < 8; ++it) dst[it] = src[it];
    }
    {   // load W^T
        int r = tid >> 1, h = (tid & 1) * 64;
        const uint4* src = (const uint4*)(Wt + (size_t)r * C + h);
        uint4* dst = (uint4*)(&Ws[r][h]);
        #pragma unroll
        for (int it = 0; it < 8; ++it) dst[it] = src[it];
    }
    __syncthreads();

    int w = tid >> 6, l = tid & 63;
    int lr = l & 15, lk = (l >> 4) * 8;
    f32x4 acc[2][8];
    #pragma unroll
    for (int m = 0; m < 2; ++m)
        #pragma unroll
        for (int n = 0; n < 8; ++n) acc[m][n] = (f32x4){0.f, 0.f, 0.f, 0.f};

    #pragma unroll
    for (int kk = 0; kk < 4; ++kk) {
        bf16x8 a0 = *(const bf16x8*)&Xs[w * 32 + lr][kk * 32 + lk];
        bf16x8 a1 = *(const bf16x8*)&Xs[w * 32 + 16 + lr][kk * 32 + lk];
        #pragma unroll
        for (int n = 0; n < 8; ++n) {
            bf16x8 b = *(const bf16x8*)&Ws[n * 16 + lr][kk * 32 + lk];
            acc[0][n] = __builtin_amdgcn_mfma_f32_16x16x32_bf16(a0, b, acc[0][n], 0, 0, 0);
            acc[1][n] = __builtin_amdgcn_mfma_f32_16x16x32_bf16(a1, b, acc[1][n], 0, 0, 0);
        }
    }

    #pragma unroll
    for (int m = 0; m < 2; ++m)
        #pragma unroll
        for (int q = 0; q < 4; ++q) {
            int rl = w * 32 + m * 16 + (l >> 4) * 4 + q;
            int dst = us[rl];
            if (dst >= 0) {
                #pragma unroll
                for (int n = 0; n < 8; ++n)
                    atomicAdd(&T[(size_t)dst * C + n * 16 + lr], acc[m][n][q]);
            }
        }
}

// ---------------- GN helpers (2 rows per 256-thread block; N must be even) ----------------
__device__ __forceinline__ float grp_sum(float v, int tid, float* red) {
    for (int off = 32; off; off >>= 1) v += __shfl_down(v, off, 64);
    __syncthreads();
    if ((tid & 63) == 0) red[tid >> 6] = v;
    __syncthreads();
    int grp = tid >> 7;
    return red[grp * 2] + red[grp * 2 + 1];
}

// stem GN A: A = gn(Y)  (no relu, f32 store)
__global__ __launch_bounds__(256) void stem_gnA(const float* __restrict__ Y,
    const float* __restrict__ g, const float* __restrict__ b, float* __restrict__ A)
{
    __shared__ float red[4];
    int tid = threadIdx.x;
    int n = blockIdx.x * 2 + (tid >> 7), c = tid & 127;
    size_t idx = (size_t)n * C + c;
    float y = Y[idx];
    float m = grp_sum(y, tid, red) * (1.f / C);
    float d = y - m;
    float var = grp_sum(d * d, tid, red) * (1.f / C);
    A[idx] = d * rsqrtf(var + EPS) * g[c] + b[c];
}

// stem GN B: r = relu(A + gn(Y)); A = r; featB = bf16(r)
__global__ __launch_bounds__(256) void stem_gnB(const float* __restrict__ Y,
    const float* __restrict__ g, const float* __restrict__ b,
    float* __restrict__ A, unsigned short* __restrict__ featB)
{
    __shared__ float red[4];
    int tid = threadIdx.x;
    int n = blockIdx.x * 2 + (tid >> 7), c = tid & 127;
    size_t idx = (size_t)n * C + c;
    float y = Y[idx];
    float m = grp_sum(y, tid, red) * (1.f / C);
    float d = y - m;
    float var = grp_sum(d * d, tid, red) * (1.f / C);
    float o = d * rsqrtf(var + EPS) * g[c] + b[c];
    float r = fmaxf(0.f, A[idx] + o);
    A[idx] = r;
    featB[idx] = f2bf(r);
}

// tail GN1: X = bf16(relu(gn(T)))
__global__ __launch_bounds__(256) void tail_gn1(const float* __restrict__ T,
    const float* __restrict__ g, const float* __restrict__ b, unsigned short* __restrict__ Xb)
{
    __shared__ float red[4];
    int tid = threadIdx.x;
    int n = blockIdx.x * 2 + (tid >> 7), c = tid & 127;
    size_t idx = (size_t)n * C + c;
    float y = T[idx];
    float m = grp_sum(y, tid, red) * (1.f / C);
    float d = y - m;
    float var = grp_sum(d * d, tid, red) * (1.f / C);
    Xb[idx] = f2bf(fmaxf(0.f, d * rsqrtf(var + EPS) * g[c] + b[c]));
}

// tail GN2: r = relu(gn(Y) + A); A = r; featB = bf16(r); Y = r (in place → final out)
__global__ __launch_bounds__(256) void tail_gn2(float* __restrict__ Y,
    const float* __restrict__ g, const float* __restrict__ b,
    float* __restrict__ A, unsigned short* __restrict__ featB)
{
    __shared__ float red[4];
    int tid = threadIdx.x;
    int n = blockIdx.x * 2 + (tid >> 7), c = tid & 127;
    size_t idx = (size_t)n * C + c;
    float y = Y[idx];
    float m = grp_sum(y, tid, red) * (1.f / C);
    float d = y - m;
    float var = grp_sum(d * d, tid, red) * (1.f / C);
    float o = d * rsqrtf(var + EPS) * g[c] + b[c];
    float r = fmaxf(0.f, A[idx] + o);
    A[idx] = r;
    featB[idx] = f2bf(r);
    Y[idx] = r;
}

extern "C" void kernel_launch(void* const* d_in, const int* in_sizes, int n_in,
                              void* d_out, int out_size, void* d_ws, size_t ws_size,
                              hipStream_t stream)
{
    const float* ctrs   = (const float*)d_in[0];
    const float* feats  = (const float*)d_in[1];
    const int*   pre_u  = (const int*)d_in[2];
    const int*   pre_v  = (const int*)d_in[3];
    const int*   suc_u  = (const int*)d_in[4];
    const int*   suc_v  = (const int*)d_in[5];
    const int*   left_u = (const int*)d_in[6];
    const int*   left_v = (const int*)d_in[7];
    const int*   right_u= (const int*)d_in[8];
    const int*   right_v= (const int*)d_in[9];
    const float* W_in1  = (const float*)d_in[10];
    const float* b_in1  = (const float*)d_in[11];
    const float* W_in2  = (const float*)d_in[12];
    const float* g_in   = (const float*)d_in[13];
    const float* bb_in  = (const float*)d_in[14];
    const float* W_seg1 = (const float*)d_in[15];
    const float* b_seg1 = (const float*)d_in[16];
    const float* W_seg2 = (const float*)d_in[17];
    const float* g_seg  = (const float*)d_in[18];
    const float* bb_seg = (const float*)d_in[19];
    const float* W_ctr  = (const float*)d_in[20];
    const float* W_pre  = (const float*)d_in[21];
    const float* W_suc  = (const float*)d_in[22];
    const float* W_left = (const float*)d_in[23];
    const float* W_right= (const float*)d_in[24];
    const float* g_norm = (const float*)d_in[25];
    const float* b_norm = (const float*)d_in[26];
    const float* W_ctr2 = (const float*)d_in[27];
    const float* g_ctr2 = (const float*)d_in[28];
    const float* b_ctr2 = (const float*)d_in[29];

    const int N  = in_sizes[0] / 2;          // 200000
    const int S  = 6;
    const int E  = in_sizes[2] / S;          // 200000
    const int E2 = in_sizes[6];              // 100000
    const int B  = in_sizes[20] / (C * C);   // 2
    const int CC = C * C;

    // workspace layout: A (f32) | featB (bf16) | WT (bf16, 34 matrices)
    float* A = (float*)d_ws;
    unsigned short* featB = (unsigned short*)(A + (size_t)N * C);
    unsigned short* WT = featB + (size_t)N * C;
    float* T = (float*)d_out;                // temp / Y scratch; final out written in place

    // weight pointer table
    WPtrs wp;
    wp.p[0] = W_in2; wp.p[1] = W_seg2;
    for (int i = 0; i < B; ++i) {
        int base = 2 + i * 16;
        wp.p[base + 0] = W_ctr + (size_t)i * CC;
        for (int s = 0; s < S; ++s) {
            wp.p[base + 1 + s] = W_pre + ((size_t)i * S + s) * CC;
            wp.p[base + 7 + s] = W_suc + ((size_t)i * S + s) * CC;
        }
        wp.p[base + 13] = W_left  + (size_t)i * CC;
        wp.p[base + 14] = W_right + (size_t)i * CC;
        wp.p[base + 15] = W_ctr2  + (size_t)i * CC;
    }

    const int GT = (N + 127) / 128;          // 1563 GEMM tiles
    const int GE = (E + 127) / 128;          // edge tiles (max over sets)
    dim3 b256(256), b128(128);

    convert_weights<<<dim3(128, 34), b128, 0, stream>>>(wp, WT);

    // ---- stem ----
    stem_pre<<<(N * C + 255) / 256, b256, 0, stream>>>(ctrs, W_in1, b_in1, featB, N);
    gemm_dense<<<GT, b256, 0, stream>>>(featB, WT + 0 * (size_t)CC, T, N);
    stem_gnA<<<N / 2, b256, 0, stream>>>(T, g_in, bb_in, A);
    stem_pre<<<(N * C + 255) / 256, b256, 0, stream>>>(feats, W_seg1, b_seg1, featB, N);
    gemm_dense<<<GT, b256, 0, stream>>>(featB, WT + 1 * (size_t)CC, T, N);
    stem_gnB<<<N / 2, b256, 0, stream>>>(T, g_seg, bb_seg, A, featB);

    // ---- fusion blocks ----
    for (int i = 0; i < B; ++i) {
        const unsigned short* WTb = WT + (size_t)(2 + i * 16) * CC;
        gemm_dense<<<GT, b256, 0, stream>>>(featB, WTb, T, N);                     // temp = feat@W_ctr
        edge_gemm<<<dim3(GE, 14), b256, 0, stream>>>(featB,
            pre_u, pre_v, suc_u, suc_v, left_u, left_v, right_u, right_v,
            WTb, T, E, E2);
        tail_gn1<<<N / 2, b256, 0, stream>>>(T, g_norm + (size_t)i * C, b_norm + (size_t)i * C, featB);
        gemm_dense<<<GT, b256, 0, stream>>>(featB, WTb + 15 * (size_t)CC, T, N);   // Y = X@W_ctr2
        tail_gn2<<<N / 2, b256, 0, stream>>>(T, g_ctr2 + (size_t)i * C, b_ctr2 + (size_t)i * C, A, featB);
    }
}